// Round 1
// baseline (36.202 us; speedup 1.0000x reference)
//
#include <hip/hip_runtime.h>

#define BB 16
#define DD 64
#define HH 128
#define WW 240
#define NS 10   // samples per level (SAMPLE_POINTS + 1)
#define NL 3    // pyramid levels
#define BLK 256

__global__ __launch_bounds__(BLK) void pcv_kernel(
    const float* __restrict__ cv,
    const int* __restrict__ radius_p,
    const float* __restrict__ disp_in,
    float* __restrict__ out)
{
    // d-major LDS: lane i always hits bank i%32 -> conflict-free random-d gather
    __shared__ float lds[DD * BLK];
    const int tid = threadIdx.x;
    const int p = blockIdx.x * BLK + tid;   // grid sized exactly: no bounds check needed
    const int w = p % WW;
    const int h = (p / WW) % HH;
    const int b = p / (WW * HH);

    const float r = (float)(*radius_p);
    // match Python: interval = (2.0 * radius) / sample_nums  (double), then weak-cast to f32
    const float interval = (float)((2.0 * (double)r) / 9.0);

    // stage full disparity column, coalesced across w
    const float* col = cv + ((size_t)b * DD + 0) * (HH * WW) + (size_t)h * WW + w;
    #pragma unroll
    for (int d = 0; d < DD; ++d) {
        lds[d * BLK + tid] = col[(size_t)d * (HH * WW)];
    }
    // no barrier: each thread reads only its own column (tid)

    const float disp = disp_in[p];
    float* outp = out + ((size_t)b * (NL * NS) + 0) * (HH * WW) + (size_t)h * WW + w;

    float rd = disp;
    int Dl = DD;
    #pragma unroll
    for (int lvl = 0; lvl < NL; ++lvl) {
        const float lower = rd - r;
        const float dmax = (float)(Dl - 1);
        #pragma unroll
        for (int s = 0; s < NS; ++s) {
            float cand = lower + (float)s * interval;
            float cc = fminf(fmaxf(ceilf(cand),  0.0f), dmax);
            float fc = fminf(fmaxf(floorf(cand), 0.0f), dmax);
            float fr = cc - cand;      // floor_rate (post-clip, as in reference)
            float cr = 1.0f - fr;      // ceil_rate
            int ic = (int)cc;
            int fi = (int)fc;
            float vc, vf;
            if (lvl == 0) {
                vc = lds[ic * BLK + tid];
                vf = lds[fi * BLK + tid];
            } else if (lvl == 1) {
                vc = 0.5f * (lds[(2 * ic) * BLK + tid] + lds[(2 * ic + 1) * BLK + tid]);
                vf = 0.5f * (lds[(2 * fi) * BLK + tid] + lds[(2 * fi + 1) * BLK + tid]);
            } else {
                float c0 = 0.5f * (lds[(4 * ic) * BLK + tid] + lds[(4 * ic + 1) * BLK + tid]);
                float c1 = 0.5f * (lds[(4 * ic + 2) * BLK + tid] + lds[(4 * ic + 3) * BLK + tid]);
                float f0 = 0.5f * (lds[(4 * fi) * BLK + tid] + lds[(4 * fi + 1) * BLK + tid]);
                float f1 = 0.5f * (lds[(4 * fi + 2) * BLK + tid] + lds[(4 * fi + 3) * BLK + tid]);
                vc = 0.5f * (c0 + c1);   // matches mean-of-means rounding
                vf = 0.5f * (f0 + f1);
            }
            outp[(size_t)(lvl * NS + s) * (HH * WW)] = vc * cr + vf * fr;
        }
        rd *= 0.5f;   // exact: ref_disp = cur_disp / 2^lvl
        Dl >>= 1;
    }
}

extern "C" void kernel_launch(void* const* d_in, const int* in_sizes, int n_in,
                              void* d_out, int out_size, void* d_ws, size_t ws_size,
                              hipStream_t stream) {
    const float* cv     = (const float*)d_in[0];
    const int*   radius = (const int*)  d_in[1];
    const float* disp   = (const float*)d_in[2];
    float*       out    = (float*)d_out;

    const int npix = BB * HH * WW;          // 491520, divisible by 256
    pcv_kernel<<<dim3(npix / BLK), dim3(BLK), 0, stream>>>(cv, radius, disp, out);
}